// Round 1
// 399.640 us; speedup vs baseline: 1.3002x; 1.3002x over previous
//
#include <hip/hip_runtime.h>
#include <hip/hip_bf16.h>

#define HEADS 8
#define DK 64
#define DV 64
#define DM 512
#define ROUNDS 2
#define SEQ 4096
#define BUCKET 64
#define NCHUNK 64
#define BATCH 4

typedef __hip_bfloat16 bf16;
__device__ __forceinline__ float b2f(bf16 x) { return __bfloat162float(x); }

// ---------------------------------------------------------------------------
// Kernel 1: hash. h[r][b][s] = argmax([q@R, -q@R]) + 1, in 1..64.
// Register-tiled fp64 GEMM: block = (r,b, 64-query tile), output 64x32 rot.
// Thread tile 2q x 4m => 8 independent fp64 accumulator chains (ILP fix for
// the serial-chain version that ran at 8% of the fp64 pipe). Q and R staged
// in LDS PRE-CONVERTED to double so the inner loop is pure v_fma_f64 +
// ds_read. Accumulation is fp64 in ascending-d order: exact argmax of the
// fp32 inputs (order-rounding ~1e-16, far below argmax tie scale).
// ---------------------------------------------------------------------------
__global__ __launch_bounds__(256) void hash_kernel(const float* __restrict__ q,
                                                   const float* __restrict__ R,
                                                   int* __restrict__ h_out) {
  int blk = blockIdx.x;
  int stile = blk & 63;
  int b = (blk >> 6) & (BATCH - 1);
  int r = blk >> 8;
  int s0 = stile << 6;
  int rb = r * BATCH + b;

  __shared__ double Qd[64 * 65];  // 33280 B, row stride 65 (bank-spread reads)
  __shared__ double Rd[64 * 32];  // 16384 B, [d][m]

  int tid = threadIdx.x;
  // compute-phase thread tile: 2 q rows x 4 m cols
  int qg = tid >> 3;  // 0..31
  int cg = tid & 7;   // 0..7
  int q0 = qg << 1;
  int m0 = cg << 2;

  // staging-phase indices: wave w loads d-offset w*16 for all 64 rows
  int qrow = tid & 63;
  int qd0 = (tid >> 6) << 4;
  const float* qbase = q + ((size_t)b * SEQ + s0 + qrow) * DM;
  const float* rbase = R + (size_t)r * DM * 32;

  float4 qreg[4];
  float rr[8];
  // prologue: load tile 0 into registers
#pragma unroll
  for (int c = 0; c < 4; ++c)
    qreg[c] = *reinterpret_cast<const float4*>(qbase + qd0 + c * 4);
#pragma unroll
  for (int j = 0; j < 8; ++j) rr[j] = rbase[j * 256 + tid];

  double acc[2][4];
#pragma unroll
  for (int qq = 0; qq < 2; ++qq)
#pragma unroll
    for (int mm = 0; mm < 4; ++mm) acc[qq][mm] = 0.0;

  for (int t = 0; t < 8; ++t) {
    // write staged registers -> LDS (convert to double once)
#pragma unroll
    for (int c = 0; c < 4; ++c) {
      double* dst = &Qd[qrow * 65 + qd0 + c * 4];
      dst[0] = (double)qreg[c].x;
      dst[1] = (double)qreg[c].y;
      dst[2] = (double)qreg[c].z;
      dst[3] = (double)qreg[c].w;
    }
#pragma unroll
    for (int j = 0; j < 8; ++j) Rd[j * 256 + tid] = (double)rr[j];
    __syncthreads();

    // issue next tile's global loads now; latency hides under compute
    if (t < 7) {
      int dt = t + 1;
#pragma unroll
      for (int c = 0; c < 4; ++c)
        qreg[c] = *reinterpret_cast<const float4*>(qbase + dt * 64 + qd0 + c * 4);
#pragma unroll
      for (int j = 0; j < 8; ++j) rr[j] = rbase[dt * 2048 + j * 256 + tid];
    }

    // 64 x (2 ds_read_b64 + 2x ds_read_b128 + 8 v_fma_f64)
#pragma unroll 4
    for (int d = 0; d < 64; ++d) {
      double qa = Qd[q0 * 65 + d];
      double qb = Qd[(q0 + 1) * 65 + d];
      double rv0 = Rd[d * 32 + m0 + 0];
      double rv1 = Rd[d * 32 + m0 + 1];
      double rv2 = Rd[d * 32 + m0 + 2];
      double rv3 = Rd[d * 32 + m0 + 3];
      acc[0][0] = fma(qa, rv0, acc[0][0]);
      acc[0][1] = fma(qa, rv1, acc[0][1]);
      acc[0][2] = fma(qa, rv2, acc[0][2]);
      acc[0][3] = fma(qa, rv3, acc[0][3]);
      acc[1][0] = fma(qb, rv0, acc[1][0]);
      acc[1][1] = fma(qb, rv1, acc[1][1]);
      acc[1][2] = fma(qb, rv2, acc[1][2]);
      acc[1][3] = fma(qb, rv3, acc[1][3]);
    }
    __syncthreads();
  }

  // argmax over 64 candidates [rot, -rot], first-max (lowest index) wins.
  double bv[2];
  int bi[2];
#pragma unroll
  for (int qq = 0; qq < 2; ++qq) {
    double v = acc[qq][0];
    int i = m0;
#pragma unroll
    for (int mm = 1; mm < 4; ++mm)
      if (acc[qq][mm] > v) { v = acc[qq][mm]; i = m0 + mm; }
#pragma unroll
    for (int mm = 0; mm < 4; ++mm) {
      double nv = -acc[qq][mm];
      if (nv > v) { v = nv; i = 32 + m0 + mm; }
    }
    bv[qq] = v;
    bi[qq] = i;
  }
  // butterfly across the 8 lanes sharing this q-pair (same wave)
#pragma unroll
  for (int off = 1; off < 8; off <<= 1) {
#pragma unroll
    for (int qq = 0; qq < 2; ++qq) {
      double ov = __shfl_xor(bv[qq], off);
      int oi = __shfl_xor(bi[qq], off);
      if (ov > bv[qq] || (ov == bv[qq] && oi < bi[qq])) { bv[qq] = ov; bi[qq] = oi; }
    }
  }
  if (cg == 0) {
#pragma unroll
    for (int qq = 0; qq < 2; ++qq)
      h_out[(size_t)rb * SEQ + s0 + q0 + qq] = bi[qq] + 1;
  }
}

// ---------------------------------------------------------------------------
// Kernel 2: stable counting sort by bucket per (r,b).
// ---------------------------------------------------------------------------
__global__ __launch_bounds__(256) void sort_kernel(const int* __restrict__ h,
                                                   int* __restrict__ sorted_idx) {
  int rb = blockIdx.x;
  const int* hp = h + (size_t)rb * SEQ;
  __shared__ unsigned char hs[SEQ];
  __shared__ int tile_cnt[64][64];
  __shared__ int tile_base[64][64];
  __shared__ int bucket_base[64];
  __shared__ int bucket_tot[64];
  for (int i = threadIdx.x; i < 64 * 64; i += 256) ((int*)tile_cnt)[i] = 0;
  __syncthreads();
  for (int s = threadIdx.x; s < SEQ; s += 256) {
    int hv = hp[s] - 1;
    hs[s] = (unsigned char)hv;
    atomicAdd(&tile_cnt[s >> 6][hv], 1);
  }
  __syncthreads();
  if (threadIdx.x < 64) {
    int bkt = threadIdx.x;
    int run = 0;
    for (int t = 0; t < 64; ++t) { tile_base[t][bkt] = run; run += tile_cnt[t][bkt]; }
    bucket_tot[bkt] = run;
  }
  __syncthreads();
  if (threadIdx.x == 0) {
    int run = 0;
    for (int bkt = 0; bkt < 64; ++bkt) { bucket_base[bkt] = run; run += bucket_tot[bkt]; }
  }
  __syncthreads();
  for (int s = threadIdx.x; s < SEQ; s += 256) {
    int t = s >> 6;
    int bkt = hs[s];
    int rank = 0;
    for (int j = t << 6; j < s; ++j) rank += (hs[j] == bkt) ? 1 : 0;
    int pos = bucket_base[bkt] + tile_base[t][bkt] + rank;
    sorted_idx[(size_t)rb * SEQ + pos] = s;
  }
}

// ---------------------------------------------------------------------------
// Kernel 3: chunked LSH attention, one round per launch (r=0 store, r=1 add).
// Block = (b, chunk n, head). 64 queries x 128 keys. fp32 math throughout;
// only V staged as bf16 (un-amplified error <= ~0.01 << 0.0825 threshold).
// LDS: A (33.8 KB) holds K fp32 then S fp32; Bq (16.9 KB) holds Q fp32 then
// V bf16. -log(cnt) bias constant per row over valid keys -> cancels.
// OUTPUT IS FP32 (reference returns float32; harness reads d_out as fp32).
// ---------------------------------------------------------------------------
__global__ __launch_bounds__(256) void attn_kernel(
    const float* __restrict__ q, const float* __restrict__ k,
    const float* __restrict__ v, const int* __restrict__ h,
    const int* __restrict__ sidx, float* __restrict__ out, int r,
    int accumulate) {
  int x = blockIdx.x;
  int hd = x & 7;
  int n = (x >> 3) & 63;
  int b = x >> 9;
  int rb = r * BATCH + b;

  __shared__ float A[128 * 66];   // 33792 B: K fp32 (128x66) -> S fp32 (64x130)
  __shared__ float Bq[64 * 66];   // 16896 B: Q fp32 (64x66) -> V bf16 (128x66)
  __shared__ int orig_w[128];
  __shared__ int hw[128];
  bf16* Vv = reinterpret_cast<bf16*>(Bq);

  int tid = threadIdx.x;
  if (tid < 128) {
    int j = tid;
    int sp = (j < 64) ? ((((n + 63) & 63) << 6) + j) : ((n << 6) + (j - 64));
    int orig = sidx[(size_t)rb * SEQ + sp];
    orig_w[j] = orig;
    hw[j] = h[(size_t)rb * SEQ + orig];
  }
  __syncthreads();

  // Stage K (128-row window) and Q (current 64 rows), fp32, stride 66.
  for (int idx = tid; idx < 128 * 16; idx += 256) {
    int j = idx >> 4, dq = idx & 15;
    float4 kk = *reinterpret_cast<const float4*>(
        k + ((size_t)b * SEQ + orig_w[j]) * DM + hd * 64 + dq * 4);
    float* dst = &A[j * 66 + dq * 4];
    dst[0] = kk.x; dst[1] = kk.y; dst[2] = kk.z; dst[3] = kk.w;
  }
  for (int idx = tid; idx < 64 * 16; idx += 256) {
    int i = idx >> 4, dq = idx & 15;
    float4 qq = *reinterpret_cast<const float4*>(
        q + ((size_t)b * SEQ + orig_w[64 + i]) * DM + hd * 64 + dq * 4);
    float* dst = &Bq[i * 66 + dq * 4];
    dst[0] = qq.x; dst[1] = qq.y; dst[2] = qq.z; dst[3] = qq.w;
  }
  __syncthreads();

  // QK^T: thread computes a 4q x 8k register tile (fp32).
  int qt = tid & 15, kt = tid >> 4;
  int q0 = qt * 4, k0 = kt * 8;
  float acc[4][8];
#pragma unroll
  for (int qq = 0; qq < 4; ++qq)
#pragma unroll
    for (int jj = 0; jj < 8; ++jj) acc[qq][jj] = 0.f;

  for (int d = 0; d < 64; ++d) {
    float kreg[8];
#pragma unroll
    for (int jj = 0; jj < 8; ++jj) kreg[jj] = A[(k0 + jj) * 66 + d];
#pragma unroll
    for (int qq = 0; qq < 4; ++qq) {
      float qv = Bq[(q0 + qq) * 66 + d];
#pragma unroll
      for (int jj = 0; jj < 8; ++jj) acc[qq][jj] = fmaf(qv, kreg[jj], acc[qq][jj]);
    }
  }
  // Scale + masks (in registers; K/Q still live in LDS until the barrier).
#pragma unroll
  for (int qq = 0; qq < 4; ++qq) {
    int i = q0 + qq;
    int hq = hw[64 + i];
#pragma unroll
    for (int jj = 0; jj < 8; ++jj) {
      int j = k0 + jj;
      float lg = acc[qq][jj] * 0.125f;
      if (hw[j] != hq) lg = -1e15f;   // bucket mask
      if (j == 64 + i) lg -= 1e5f;    // self mask (diagonal of 128-window)
      acc[qq][jj] = lg;
    }
  }
  __syncthreads();  // all K/Q reads complete

  // Write S into A (stride 130); load V (bf16) into Bq's bytes.
#pragma unroll
  for (int qq = 0; qq < 4; ++qq)
#pragma unroll
    for (int jj = 0; jj < 8; ++jj) A[(q0 + qq) * 130 + k0 + jj] = acc[qq][jj];
  for (int idx = tid; idx < 128 * 16; idx += 256) {
    int j = idx >> 4, dq = idx & 15;
    float4 vv = *reinterpret_cast<const float4*>(
        v + ((size_t)b * SEQ + orig_w[j]) * DM + hd * 64 + dq * 4);
    bf16* dst = &Vv[j * 66 + dq * 4];
    dst[0] = __float2bfloat16(vv.x);
    dst[1] = __float2bfloat16(vv.y);
    dst[2] = __float2bfloat16(vv.z);
    dst[3] = __float2bfloat16(vv.w);
  }
  __syncthreads();

  // Softmax over 128 keys: 4 threads per row (segments of 32), fp32.
  {
    int row = tid >> 2, seg = tid & 3;
    float* Srow = A + row * 130 + seg * 32;
    float mx = -INFINITY;
#pragma unroll 8
    for (int t = 0; t < 32; ++t) mx = fmaxf(mx, Srow[t]);
    mx = fmaxf(mx, __shfl_xor(mx, 1));
    mx = fmaxf(mx, __shfl_xor(mx, 2));
    float sm = 0.f;
#pragma unroll 8
    for (int t = 0; t < 32; ++t) {
      float ev = __expf(Srow[t] - mx);
      Srow[t] = ev;
      sm += ev;
    }
    sm += __shfl_xor(sm, 1);
    sm += __shfl_xor(sm, 2);
    float inv = 1.0f / sm;
#pragma unroll 8
    for (int t = 0; t < 32; ++t) Srow[t] *= inv;
  }
  __syncthreads();

  // P @ V: thread computes a 4q x 4dv register tile.
  int dv0 = (tid >> 4) * 4;  // q0 unchanged
  float o[4][4];
#pragma unroll
  for (int qq = 0; qq < 4; ++qq)
#pragma unroll
    for (int dd = 0; dd < 4; ++dd) o[qq][dd] = 0.f;

  for (int l = 0; l < 128; ++l) {
    float vv[4];
#pragma unroll
    for (int dd = 0; dd < 4; ++dd) vv[dd] = b2f(Vv[l * 66 + dv0 + dd]);
#pragma unroll
    for (int qq = 0; qq < 4; ++qq) {
      float pv = A[(q0 + qq) * 130 + l];
#pragma unroll
      for (int dd = 0; dd < 4; ++dd) o[qq][dd] = fmaf(pv, vv[dd], o[qq][dd]);
    }
  }

  // FP32 output, scatter back through the inverse permutation.
#pragma unroll
  for (int qq = 0; qq < 4; ++qq) {
    int i = q0 + qq;
    size_t base = ((size_t)b * SEQ + orig_w[64 + i]) * DM + hd * 64 + dv0;
    if (accumulate) {
#pragma unroll
      for (int dd = 0; dd < 4; ++dd) out[base + dd] += o[qq][dd];
    } else {
#pragma unroll
      for (int dd = 0; dd < 4; ++dd) out[base + dd] = o[qq][dd];
    }
  }
}

extern "C" void kernel_launch(void* const* d_in, const int* in_sizes, int n_in,
                              void* d_out, int out_size, void* d_ws,
                              size_t ws_size, hipStream_t stream) {
  (void)out_size; (void)ws_size;
  const int R_ELEMS = ROUNDS * DM * 32;
  const float *q, *k, *v, *R;
  if (n_in >= 4 && in_sizes[0] == R_ELEMS) {  // defensive; dict order is live
    R = (const float*)d_in[0];
    k = (const float*)d_in[1];
    q = (const float*)d_in[2];
    v = (const float*)d_in[3];
  } else {
    q = (const float*)d_in[0];
    k = (const float*)d_in[1];
    v = (const float*)d_in[2];
    R = (const float*)d_in[3];
  }
  float* out = (float*)d_out;  // REFERENCE OUTPUT IS FP32
  char* ws = (char*)d_ws;
  int* h = (int*)ws;                                   // 128 KB
  int* sidx = (int*)(ws + ROUNDS * BATCH * SEQ * 4);   // 128 KB

  hash_kernel<<<ROUNDS * BATCH * (SEQ / 64), 256, 0, stream>>>(q, R, h);
  sort_kernel<<<ROUNDS * BATCH, 256, 0, stream>>>(h, sidx);
  attn_kernel<<<BATCH * NCHUNK * HEADS, 256, 0, stream>>>(q, k, v, h, sidx, out, 0, 0);
  attn_kernel<<<BATCH * NCHUNK * HEADS, 256, 0, stream>>>(q, k, v, h, sidx, out, 1, 1);
}